// Round 4
// baseline (513.579 us; speedup 1.0000x reference)
//
#include <hip/hip_runtime.h>
#include <hip/hip_bf16.h>
#include <stdint.h>

#define IN_F 4096
#define OUT_F 4096

typedef __attribute__((ext_vector_type(8))) __bf16 bf16x8;
typedef __attribute__((ext_vector_type(4))) float f32x4;

__device__ __forceinline__ void gl_lds_16(const void* g, void* l) {
    __builtin_amdgcn_global_load_lds((const __attribute__((address_space(1))) void*)g,
                                     (__attribute__((address_space(3))) void*)l,
                                     16, 0, 0);
}

// ---- fused: x fp32->bf16 cvt  +  dense-W build from sorted COO ----
// cvt blocks: 8 elems/thread, 16B loads+stores.
// build blocks: each owns 2048 consecutive W elems; binary-search sorted idx,
// emit zeros/run-sums as coalesced bf16x8 stores. Replaces memset+random-scatter
// (saves a full 32MB memset pass + uncoalesced 2B writes). Summation order per
// W element is idx-sorted order == previous scatter's order -> bit-identical.
__global__ void cvt_and_build(const float* __restrict__ x, __bf16* __restrict__ Xb, int n8,
                              const float* __restrict__ vals, const int* __restrict__ idx,
                              __bf16* __restrict__ W, int nnz, int cvtBlocks) {
    if ((int)blockIdx.x < cvtBlocks) {
        int i = blockIdx.x * blockDim.x + threadIdx.x;
        if (i < n8) {
            const float4* src = (const float4*)(x + (size_t)i * 8);
            float4 v0 = src[0], v1 = src[1];
            bf16x8 o;
            o[0] = (__bf16)v0.x; o[1] = (__bf16)v0.y; o[2] = (__bf16)v0.z; o[3] = (__bf16)v0.w;
            o[4] = (__bf16)v1.x; o[5] = (__bf16)v1.y; o[6] = (__bf16)v1.z; o[7] = (__bf16)v1.w;
            *(bf16x8*)(Xb + (size_t)i * 8) = o;
        }
    } else {
        const int b = (int)blockIdx.x - cvtBlocks;   // 0..8191
        const int s = b << 11;                       // block owns W[s, s+2048)
        __shared__ int slo, shi;
        if (threadIdx.x == 0) {                      // lo = lower_bound(idx, s)
            int lo = 0, hi = nnz;
            while (lo < hi) { int m = (lo + hi) >> 1; if (idx[m] < s) lo = m + 1; else hi = m; }
            slo = lo;
        }
        if (threadIdx.x == 1) {                      // hi = lower_bound(idx, s+2048)
            int lo = 0, hi = nnz;
            const int e = s + 2048;
            while (lo < hi) { int m = (lo + hi) >> 1; if (idx[m] < e) lo = m + 1; else hi = m; }
            shi = lo;
        }
        __syncthreads();
        const int ts = s + (int)threadIdx.x * 8;     // this thread's 8 W elems
        int l = slo, h = shi;                        // narrow per-thread lower_bound(ts)
        while (l < h) { int m = (l + h) >> 1; if (idx[m] < ts) l = m + 1; else h = m; }
        int j = l;
        bf16x8 o;
#pragma unroll
        for (int k = 0; k < 8; ++k) {                // static k -> named regs, no scratch
            float a = 0.0f;
            while (j < shi && idx[j] == ts + k) { a += vals[j]; ++j; }
            o[k] = (__bf16)a;
        }
        *(bf16x8*)(W + ts) = o;
    }
}

// ---- GEMM: C[M,N] = A[M,K] * B[N,K]^T + bias,  bf16 in / fp32 out ----
// 256x256 tile, BK=32, 8 waves (2Mx4N), quad-buffered LDS, prefetch distance 3,
// counted vmcnt(8), ONE barrier per K-tile (R3-measured: LDS-read-pipe-bound,
// 4 extra cyc/read bank conflict).
// R4 change: chunk-XOR LDS swizzle. Measured conflict mechanism: quarter-wave
// (16 lanes, fixed lq) reads 16 rows at same 16B chunk -> 8 of 32 banks, 8
// words/bank. Fix: phys_chunk = logical_chunk ^ ((row>>1)&3); rows 0-7 of a
// quarter-group then cover all 32 banks exactly once. Both-sides-or-neither:
// LDS dest stays linear (global_load_lds constraint), GLOBAL source chunk is
// pre-permuted; read XOR folds into per-lane constant ((lr>>1)&3 — row bases
// are multiples of 16), zero extra VALU in the loop.
#define BM 256
#define BN 256
#define BK 32
#define NT (IN_F / BK)   // 128 K-tiles

__global__ __launch_bounds__(512, 2) void gemm_bf16_bt(
    const __bf16* __restrict__ A, const __bf16* __restrict__ B,
    const float* __restrict__ bias, float* __restrict__ C,
    int M, int N, int K)
{
    __shared__ __align__(128) __bf16 lds[4][16384];

    const int t512 = threadIdx.x;          // 0..511
    const int wave = t512 >> 6;            // 0..7
    const int lane = t512 & 63;
    const int wm = wave >> 2;              // 0..1  (M half)
    const int wn = wave & 3;               // 0..3  (N quarter)
    const int lq = lane >> 4;              // 0..3
    const int lr = lane & 15;              // 0..15

    // XCD swizzle: grid is exactly 512 = 8 XCDs x 64 contiguous slots
    const int bid  = blockIdx.x;
    const int wgid = (bid & 7) * 64 + (bid >> 3);
    const int mt = wgid >> 4;              // 0..31
    const int nt = wgid & 15;              // 0..15
    const int tileM = mt * BM;
    const int tileN = nt * BN;

    // staging: thread u covers row u>>2; DEST chunk u&3 is linear, SOURCE chunk
    // is the swizzle-inverse: c = (u&3) ^ ((row>>1)&3) = (u&3) ^ ((u>>3)&3).
    const int srow = t512 >> 2;            // 0..127
    const int scol = ((t512 & 3) ^ ((t512 >> 3) & 3)) * 8;   // element col of 16B chunk

    const __bf16* gA0 = A + (size_t)(tileM + srow) * K + scol;
    const __bf16* gA1 = A + (size_t)(tileM + 128 + srow) * K + scol;
    const __bf16* gB0 = B + (size_t)(tileN + srow) * K + scol;
    const __bf16* gB1 = B + (size_t)(tileN + 128 + srow) * K + scol;

#define STAGE_A(buf, k0) do { \
        gl_lds_16(gA0 + (k0), &lds[buf][0]    + t512 * 8); \
        gl_lds_16(gA1 + (k0), &lds[buf][4096] + t512 * 8); } while (0)
#define STAGE_B(buf, k0) do { \
        gl_lds_16(gB0 + (k0), &lds[buf][8192]         + t512 * 8); \
        gl_lds_16(gB1 + (k0), &lds[buf][8192 + 4096]  + t512 * 8); } while (0)

    // fragment read offsets with matching XOR: phys chunk = lq ^ ((row>>1)&3);
    // row = base16 + lr with base16 % 16 == 0  ->  ((row>>1)&3) == ((lr>>1)&3).
    const int cswz = (lq ^ ((lr >> 1) & 3)) * 8;
    const int aoff = (wm * 128 + lr) * BK + cswz;            // af[mi] at +mi*512
    const int boff = 8192 + (wn * 64 + lr) * BK + cswz;      // bg[ni] at +ni*512

    f32x4 acc[8][4] = {};

    // ---- prologue: stage tiles 0,1,2; wait tile-0 loads; sync ----
    STAGE_A(0, 0);   STAGE_B(0, 0);
    STAGE_A(1, 32);  STAGE_B(1, 32);
    STAGE_A(2, 64);  STAGE_B(2, 64);
    asm volatile("s_waitcnt vmcnt(8)" ::: "memory");
    __builtin_amdgcn_s_barrier();
    asm volatile("" ::: "memory");

    for (int t = 0; t < NT; ++t) {
        const __bf16* sbuf = &lds[t & 3][0];
        const int  pk = (t + 3) * BK;
        const int  pb = (t + 3) & 3;       // == (t-1)&3: readers drained at t-1's barrier
        const bool pf = (t + 3) < NT;

        // issue prefetch first (longest latency), then all 12 fragment reads
        if (pf) { STAGE_A(pb, pk); STAGE_B(pb, pk); }

        bf16x8 af[8], bg[4];
#pragma unroll
        for (int mi = 0; mi < 8; ++mi) af[mi] = *(const bf16x8*)&sbuf[aoff + mi * 512];
#pragma unroll
        for (int ni = 0; ni < 4; ++ni) bg[ni] = *(const bf16x8*)&sbuf[boff + ni * 512];

        __builtin_amdgcn_s_setprio(1);
#pragma unroll
        for (int mi = 0; mi < 8; ++mi)
#pragma unroll
            for (int ni = 0; ni < 4; ++ni)
                acc[mi][ni] = __builtin_amdgcn_mfma_f32_16x16x32_bf16(af[mi], bg[ni], acc[mi][ni], 0, 0, 0);
        __builtin_amdgcn_s_setprio(0);

        // drain own ds_reads, then counted vmcnt: steady state leaves tiles
        // t+2,t+3 (8 loads) in flight; drain only at tail.
        asm volatile("s_waitcnt lgkmcnt(0)" ::: "memory");
        if (t < NT - 3)       asm volatile("s_waitcnt vmcnt(8)" ::: "memory");
        else if (t == NT - 3) asm volatile("s_waitcnt vmcnt(4)" ::: "memory");
        else if (t == NT - 2) asm volatile("s_waitcnt vmcnt(0)" ::: "memory");
        __builtin_amdgcn_s_barrier();
        asm volatile("" ::: "memory");
    }

    // ---- epilogue: C/D layout col=lane&15, row=(lane>>4)*4+reg  [m89-verified] ----
    float bv[4];
#pragma unroll
    for (int ni = 0; ni < 4; ++ni) bv[ni] = bias[tileN + wn * 64 + ni * 16 + lr];
#pragma unroll
    for (int mi = 0; mi < 8; ++mi) {
#pragma unroll
        for (int ni = 0; ni < 4; ++ni) {
            const int gn = tileN + wn * 64 + ni * 16 + lr;
#pragma unroll
            for (int r = 0; r < 4; ++r) {
                const int gm = tileM + wm * 128 + mi * 16 + lq * 4 + r;
                C[(size_t)gm * N + gn] = acc[mi][ni][r] + bv[ni];
            }
        }
    }
#undef STAGE_A
#undef STAGE_B
}

extern "C" void kernel_launch(void* const* d_in, const int* in_sizes, int n_in,
                              void* d_out, int out_size, void* d_ws, size_t ws_size,
                              hipStream_t stream) {
    const float* x    = (const float*)d_in[0];   // (4,2048,4096) fp32
    const float* vals = (const float*)d_in[1];   // (NNZ,) fp32
    const float* bias = (const float*)d_in[2];   // (4096,) fp32
    const int*   idx  = (const int*)d_in[3];     // (NNZ,) sorted flat indices
    float* out = (float*)d_out;                  // (4,2048,4096) fp32

    const int nnz = in_sizes[1];
    const int K = IN_F, N = OUT_F;
    const int M = in_sizes[0] / K;               // 8192

    // workspace: [0,32M) W bf16 | [32M,96M) x bf16
    char* ws = (char*)d_ws;
    __bf16* Wb = (__bf16*)ws;
    __bf16* Xb = (__bf16*)(ws + (size_t)32 * 1024 * 1024);

    const int wElems = N * K;                    // 16777216
    const int xElems = M * K;                    // 33554432
    const int n8 = xElems / 8;                   // 4194304 cvt threads
    const int cvtBlocks = n8 / 256;              // 16384
    const int buildBlocks = wElems / 2048;       // 8192 (covers W exactly, no memset)

    cvt_and_build<<<cvtBlocks + buildBlocks, 256, 0, stream>>>(
        x, Xb, n8, vals, idx, Wb, nnz, cvtBlocks);

    gemm_bf16_bt<<<(M / BM) * (N / BN), 512, 0, stream>>>(Xb, Wb, bias, out, M, N, K);
}

// Round 5
// 467.199 us; speedup vs baseline: 1.0993x; 1.0993x over previous
//
#include <hip/hip_runtime.h>
#include <hip/hip_bf16.h>
#include <stdint.h>

#define IN_F 4096
#define OUT_F 4096

typedef __attribute__((ext_vector_type(8))) __bf16 bf16x8;
typedef __attribute__((ext_vector_type(4))) float f32x4;

__device__ __forceinline__ void gl_lds_16(const void* g, void* l) {
    __builtin_amdgcn_global_load_lds((const __attribute__((address_space(1))) void*)g,
                                     (__attribute__((address_space(3))) void*)l,
                                     16, 0, 0);
}

// ---- fused: x fp32->bf16 (8 elems/thread, 16B stores) + sorted-COO scatter ----
// (reverted to R3 form: measured 210 us vs 261 us for the binary-search build —
// the per-block serial binary search stalled whole blocks behind __syncthreads)
__global__ void cvt_and_scatter(const float* __restrict__ x, __bf16* __restrict__ Xb, int n8,
                                const float* __restrict__ vals, const int* __restrict__ idx,
                                __bf16* __restrict__ W, int nnz, int cvtBlocks) {
    if ((int)blockIdx.x < cvtBlocks) {
        int i = blockIdx.x * blockDim.x + threadIdx.x;
        if (i < n8) {
            const float4* src = (const float4*)(x + (size_t)i * 8);
            float4 v0 = src[0], v1 = src[1];
            bf16x8 o;
            o[0] = (__bf16)v0.x; o[1] = (__bf16)v0.y; o[2] = (__bf16)v0.z; o[3] = (__bf16)v0.w;
            o[4] = (__bf16)v1.x; o[5] = (__bf16)v1.y; o[6] = (__bf16)v1.z; o[7] = (__bf16)v1.w;
            *(bf16x8*)(Xb + (size_t)i * 8) = o;
        }
    } else {
        // flat_idx sorted -> duplicate runs adjacent; run owner sums fp32, stores bf16.
        int i = (blockIdx.x - cvtBlocks) * blockDim.x + threadIdx.x;
        if (i >= nnz) return;
        const int id = idx[i];
        if (i > 0 && idx[i - 1] == id) return;
        float s = vals[i];
        for (int j = i + 1; j < nnz && idx[j] == id; ++j) s += vals[j];
        W[id] = (__bf16)s;
    }
}

// ---- GEMM: C[M,N] = A[M,K] * B[N,K]^T + bias,  bf16 in / fp32 out ----
// 256x256 tile, BK=32, 8 waves (2Mx4N), quad-buffered LDS, prefetch distance 3.
// R4 gave conflict-free LDS (chunk-XOR swizzle, SQ_LDS_BANK_CONFLICT=0) but the
// LDS-read pipe (1152 cyc/tile) and MFMA pipe (1241 cyc/tile) ran SERIALLY:
// each wave's MFMAs depended on its just-issued reads, and barrier lockstep
// phase-aligned all waves. R5: register double-buffered fragments — at tile t,
// issue ds_reads for frags(t+1) into the alternate set, then MFMA on frags(t).
// Reads and MFMAs are independent -> pipes overlap; per-tile -> ~max(1241,1408).
// Sync derivation:
//   - reads@t target buf (t+1)&3. ALL-waves staging certification must come from
//     barrier@t-1, so the counted wait is vmcnt(4) (STAGE(t+2) done) BEFORE each
//     end-of-tile barrier. Prologue: vmcnt(4) certifies stages 0 AND 1.
//   - WAR: STAGE@t overwrites buf (t-1)&3; its readers (reads@t-2, consumed by
//     MFMAs@t-1 whose lgkm wait precedes barrier@t-1) are 1+ barriers upstream.
//   - Tail: t==NT-3 -> vmcnt(0); later tiles need no wait; t==NT-1 no barrier.
// Unroll x2 with NAMED frag sets (runtime-indexed reg arrays -> scratch).
#define BM 256
#define BN 256
#define BK 32
#define NT (IN_F / BK)   // 128 K-tiles

__global__ __launch_bounds__(512, 2) void gemm_bf16_bt(
    const __bf16* __restrict__ A, const __bf16* __restrict__ B,
    const float* __restrict__ bias, float* __restrict__ C,
    int M, int N, int K)
{
    __shared__ __align__(128) __bf16 lds[4][16384];

    const int t512 = threadIdx.x;          // 0..511
    const int wave = t512 >> 6;            // 0..7
    const int lane = t512 & 63;
    const int wm = wave >> 2;              // 0..1  (M half)
    const int wn = wave & 3;               // 0..3  (N quarter)
    const int lq = lane >> 4;              // 0..3
    const int lr = lane & 15;              // 0..15

    // XCD swizzle: grid is exactly 512 = 8 XCDs x 64 contiguous slots
    const int bid  = blockIdx.x;
    const int wgid = (bid & 7) * 64 + (bid >> 3);
    const int mt = wgid >> 4;              // 0..31
    const int nt = wgid & 15;              // 0..15
    const int tileM = mt * BM;
    const int tileN = nt * BN;

    // staging: thread u covers row u>>2; DEST chunk u&3 linear (global_load_lds),
    // SOURCE chunk swizzle-inverse: c = (u&3) ^ ((row>>1)&3) = (u&3) ^ ((u>>3)&3).
    const int srow = t512 >> 2;            // 0..127
    const int scol = ((t512 & 3) ^ ((t512 >> 3) & 3)) * 8;

    const __bf16* gA0 = A + (size_t)(tileM + srow) * K + scol;
    const __bf16* gA1 = A + (size_t)(tileM + 128 + srow) * K + scol;
    const __bf16* gB0 = B + (size_t)(tileN + srow) * K + scol;
    const __bf16* gB1 = B + (size_t)(tileN + 128 + srow) * K + scol;

#define STAGE_A(buf, k0) do { \
        gl_lds_16(gA0 + (k0), &lds[buf][0]    + t512 * 8); \
        gl_lds_16(gA1 + (k0), &lds[buf][4096] + t512 * 8); } while (0)
#define STAGE_B(buf, k0) do { \
        gl_lds_16(gB0 + (k0), &lds[buf][8192]         + t512 * 8); \
        gl_lds_16(gB1 + (k0), &lds[buf][8192 + 4096]  + t512 * 8); } while (0)

    // fragment read offsets with matching XOR (row bases are multiples of 16):
    const int cswz = (lq ^ ((lr >> 1) & 3)) * 8;
    const int aoff = (wm * 128 + lr) * BK + cswz;            // fa[mi] at +mi*512
    const int boff = 8192 + (wn * 64 + lr) * BK + cswz;      // fb[ni] at +ni*512

    f32x4 acc[8][4] = {};
    bf16x8 fa0[8], fb0[4], fa1[8], fb1[4];

#define TILE(T, FAc, FBc, FAn, FBn) do {                                        \
        const int t_ = (T);                                                     \
        if (t_ + 3 < NT) {                                                      \
            const int pb_ = (t_ + 3) & 3; const int pk_ = (t_ + 3) * BK;        \
            STAGE_A(pb_, pk_); STAGE_B(pb_, pk_);                               \
        }                                                                       \
        if (t_ + 1 < NT) {                                                      \
            const __bf16* nb_ = &lds[(t_ + 1) & 3][0];                          \
            _Pragma("unroll") for (int mi = 0; mi < 8; ++mi)                    \
                FAn[mi] = *(const bf16x8*)&nb_[aoff + mi * 512];                \
            _Pragma("unroll") for (int ni = 0; ni < 4; ++ni)                    \
                FBn[ni] = *(const bf16x8*)&nb_[boff + ni * 512];                \
        }                                                                       \
        __builtin_amdgcn_sched_barrier(0);                                      \
        __builtin_amdgcn_s_setprio(1);                                          \
        _Pragma("unroll") for (int mi = 0; mi < 8; ++mi)                        \
            _Pragma("unroll") for (int ni = 0; ni < 4; ++ni)                    \
                acc[mi][ni] = __builtin_amdgcn_mfma_f32_16x16x32_bf16(          \
                    FAc[mi], FBc[ni], acc[mi][ni], 0, 0, 0);                    \
        __builtin_amdgcn_s_setprio(0);                                          \
        if (t_ < NT - 3)       asm volatile("s_waitcnt vmcnt(4)" ::: "memory"); \
        else if (t_ == NT - 3) asm volatile("s_waitcnt vmcnt(0)" ::: "memory"); \
        if (t_ < NT - 1) {                                                      \
            __builtin_amdgcn_s_barrier();                                       \
            asm volatile("" ::: "memory");                                      \
        }                                                                       \
    } while (0)

    // ---- prologue: stage 0,1,2; certify stages 0+1 for ALL waves; frags(0) ----
    STAGE_A(0, 0);   STAGE_B(0, 0);
    STAGE_A(1, 32);  STAGE_B(1, 32);
    STAGE_A(2, 64);  STAGE_B(2, 64);
    asm volatile("s_waitcnt vmcnt(4)" ::: "memory");
    __builtin_amdgcn_s_barrier();
    asm volatile("" ::: "memory");
    {
        const __bf16* nb_ = &lds[0][0];
#pragma unroll
        for (int mi = 0; mi < 8; ++mi) fa0[mi] = *(const bf16x8*)&nb_[aoff + mi * 512];
#pragma unroll
        for (int ni = 0; ni < 4; ++ni) fb0[ni] = *(const bf16x8*)&nb_[boff + ni * 512];
    }

    for (int t = 0; t < NT; t += 2) {
        TILE(t,     fa0, fb0, fa1, fb1);
        TILE(t + 1, fa1, fb1, fa0, fb0);
    }

    // ---- epilogue: C/D layout col=lane&15, row=(lane>>4)*4+reg  [m89-verified] ----
    float bv[4];
#pragma unroll
    for (int ni = 0; ni < 4; ++ni) bv[ni] = bias[tileN + wn * 64 + ni * 16 + lr];
#pragma unroll
    for (int mi = 0; mi < 8; ++mi) {
#pragma unroll
        for (int ni = 0; ni < 4; ++ni) {
            const int gn = tileN + wn * 64 + ni * 16 + lr;
#pragma unroll
            for (int r = 0; r < 4; ++r) {
                const int gm = tileM + wm * 128 + mi * 16 + lq * 4 + r;
                C[(size_t)gm * N + gn] = acc[mi][ni][r] + bv[ni];
            }
        }
    }
#undef TILE
#undef STAGE_A
#undef STAGE_B
}

extern "C" void kernel_launch(void* const* d_in, const int* in_sizes, int n_in,
                              void* d_out, int out_size, void* d_ws, size_t ws_size,
                              hipStream_t stream) {
    const float* x    = (const float*)d_in[0];   // (4,2048,4096) fp32
    const float* vals = (const float*)d_in[1];   // (NNZ,) fp32
    const float* bias = (const float*)d_in[2];   // (4096,) fp32
    const int*   idx  = (const int*)d_in[3];     // (NNZ,) sorted flat indices
    float* out = (float*)d_out;                  // (4,2048,4096) fp32

    const int nnz = in_sizes[1];
    const int K = IN_F, N = OUT_F;
    const int M = in_sizes[0] / K;               // 8192

    // workspace: [0,32M) W bf16 | [32M,96M) x bf16
    char* ws = (char*)d_ws;
    __bf16* Wb = (__bf16*)ws;
    __bf16* Xb = (__bf16*)(ws + (size_t)32 * 1024 * 1024);

    const int wElems = N * K;                    // 16777216
    const int xElems = M * K;                    // 33554432
    const int n8 = xElems / 8;                   // 4194304 cvt threads
    const int cvtBlocks = n8 / 256;              // 16384
    const int scatBlocks = (nnz + 255) / 256;    // 6554

    hipMemsetAsync(Wb, 0, (size_t)wElems * sizeof(__bf16), stream);
    cvt_and_scatter<<<cvtBlocks + scatBlocks, 256, 0, stream>>>(
        x, Xb, n8, vals, idx, Wb, nnz, cvtBlocks);

    gemm_bf16_bt<<<(M / BM) * (N / BN), 512, 0, stream>>>(Xb, Wb, bias, out, M, N, K);
}

// Round 6
// 463.608 us; speedup vs baseline: 1.1078x; 1.0077x over previous
//
#include <hip/hip_runtime.h>
#include <hip/hip_bf16.h>
#include <stdint.h>

#define IN_F 4096
#define OUT_F 4096

typedef __attribute__((ext_vector_type(8))) __bf16 bf16x8;
typedef __attribute__((ext_vector_type(4))) float f32x4;

__device__ __forceinline__ void gl_lds_16(const void* g, void* l) {
    __builtin_amdgcn_global_load_lds((const __attribute__((address_space(1))) void*)g,
                                     (__attribute__((address_space(3))) void*)l,
                                     16, 0, 0);
}

// ---- fused: x fp32->bf16 (8 elems/thread, 16B stores) + sorted-COO scatter ----
__global__ void cvt_and_scatter(const float* __restrict__ x, __bf16* __restrict__ Xb, int n8,
                                const float* __restrict__ vals, const int* __restrict__ idx,
                                __bf16* __restrict__ W, int nnz, int cvtBlocks) {
    if ((int)blockIdx.x < cvtBlocks) {
        int i = blockIdx.x * blockDim.x + threadIdx.x;
        if (i < n8) {
            const float4* src = (const float4*)(x + (size_t)i * 8);
            float4 v0 = src[0], v1 = src[1];
            bf16x8 o;
            o[0] = (__bf16)v0.x; o[1] = (__bf16)v0.y; o[2] = (__bf16)v0.z; o[3] = (__bf16)v0.w;
            o[4] = (__bf16)v1.x; o[5] = (__bf16)v1.y; o[6] = (__bf16)v1.z; o[7] = (__bf16)v1.w;
            *(bf16x8*)(Xb + (size_t)i * 8) = o;
        }
    } else {
        // flat_idx sorted -> duplicate runs adjacent; run owner sums fp32, stores bf16.
        int i = (blockIdx.x - cvtBlocks) * blockDim.x + threadIdx.x;
        if (i >= nnz) return;
        const int id = idx[i];
        if (i > 0 && idx[i - 1] == id) return;
        float s = vals[i];
        for (int j = i + 1; j < nnz && idx[j] == id; ++j) s += vals[j];
        W[id] = (__bf16)s;
    }
}

// ---- GEMM: C[M,N] = A[M,K] * B[N,K]^T + bias,  bf16 in / fp32 out ----
// 256x256 tile, BK=32, 8 waves (2Mx4N), quad-buffered LDS, prefetch distance 3,
// chunk-XOR swizzle (R4: conflicts=0), register-double-buffered fragments (R5).
// R6: issue-level interleave. R5 measured per-tile = 1024(MFMA) + 1152(LDS) +
// barrier = serial, because sched_barrier(0) pinned ALL 12 ds_reads before ALL
// 32 MFMAs: 8 waves dump 96 b128 reads into the per-CU LDS pipe, the queue
// backpressures, and waves stall mid-read-issue before reaching their MFMAs.
// Fix: sched_group_barrier chain prescribing 4 x {1 VMEM, 3 DS_READ, 8 MFMA}
// per tile -> both pipes fed continuously; LDS (1152/CU) becomes the binding
// pipe. Reads+MFMAs must share a basic block: main loop peeled to tiles 0..123
// (no branches); tail tiles 124..127 use the literal-folded TILE macro.
// Sync schedule unchanged from R5 (verified): vmcnt(4) certifies STAGE@t-1
// (tile t+2) before barrier@t; reads@t (buf (t+1)&3) covered by barrier@t-1.
#define BM 256
#define BN 256
#define BK 32
#define NT (IN_F / BK)   // 128 K-tiles

__global__ __launch_bounds__(512, 2) void gemm_bf16_bt(
    const __bf16* __restrict__ A, const __bf16* __restrict__ B,
    const float* __restrict__ bias, float* __restrict__ C,
    int M, int N, int K)
{
    __shared__ __align__(128) __bf16 lds[4][16384];

    const int t512 = threadIdx.x;          // 0..511
    const int wave = t512 >> 6;            // 0..7
    const int lane = t512 & 63;
    const int wm = wave >> 2;              // 0..1  (M half)
    const int wn = wave & 3;               // 0..3  (N quarter)
    const int lq = lane >> 4;              // 0..3
    const int lr = lane & 15;              // 0..15

    // XCD swizzle: grid is exactly 512 = 8 XCDs x 64 contiguous slots
    const int bid  = blockIdx.x;
    const int wgid = (bid & 7) * 64 + (bid >> 3);
    const int mt = wgid >> 4;              // 0..31
    const int nt = wgid & 15;              // 0..15
    const int tileM = mt * BM;
    const int tileN = nt * BN;

    // staging: thread u covers row u>>2; DEST chunk u&3 linear (global_load_lds),
    // SOURCE chunk swizzle-inverse: c = (u&3) ^ ((row>>1)&3) = (u&3) ^ ((u>>3)&3).
    const int srow = t512 >> 2;            // 0..127
    const int scol = ((t512 & 3) ^ ((t512 >> 3) & 3)) * 8;

    const __bf16* gA0 = A + (size_t)(tileM + srow) * K + scol;
    const __bf16* gA1 = A + (size_t)(tileM + 128 + srow) * K + scol;
    const __bf16* gB0 = B + (size_t)(tileN + srow) * K + scol;
    const __bf16* gB1 = B + (size_t)(tileN + 128 + srow) * K + scol;

#define STAGE_A(buf, k0) do { \
        gl_lds_16(gA0 + (k0), &lds[buf][0]    + t512 * 8); \
        gl_lds_16(gA1 + (k0), &lds[buf][4096] + t512 * 8); } while (0)
#define STAGE_B(buf, k0) do { \
        gl_lds_16(gB0 + (k0), &lds[buf][8192]         + t512 * 8); \
        gl_lds_16(gB1 + (k0), &lds[buf][8192 + 4096]  + t512 * 8); } while (0)

    // fragment read offsets with matching XOR (row bases are multiples of 16):
    const int cswz = (lq ^ ((lr >> 1) & 3)) * 8;
    const int aoff = (wm * 128 + lr) * BK + cswz;            // fa[mi] at +mi*512
    const int boff = 8192 + (wn * 64 + lr) * BK + cswz;      // fb[ni] at +ni*512

    f32x4 acc[8][4] = {};
    bf16x8 fa0[8], fb0[4], fa1[8], fb1[4];

// main-loop tile: NO branches (tiles 0..123 all stage+read), SGB interleave.
#define TILE_MAIN(T, FAc, FBc, FAn, FBn) do {                                   \
        const int t_ = (T);                                                     \
        const int pb_ = (t_ + 3) & 3; const int pk_ = (t_ + 3) * BK;            \
        STAGE_A(pb_, pk_); STAGE_B(pb_, pk_);                                   \
        const __bf16* nb_ = &lds[(t_ + 1) & 3][0];                              \
        _Pragma("unroll") for (int mi = 0; mi < 8; ++mi)                        \
            FAn[mi] = *(const bf16x8*)&nb_[aoff + mi * 512];                    \
        _Pragma("unroll") for (int ni = 0; ni < 4; ++ni)                        \
            FBn[ni] = *(const bf16x8*)&nb_[boff + ni * 512];                    \
        __builtin_amdgcn_s_setprio(1);                                          \
        _Pragma("unroll") for (int mi = 0; mi < 8; ++mi)                        \
            _Pragma("unroll") for (int ni = 0; ni < 4; ++ni)                    \
                acc[mi][ni] = __builtin_amdgcn_mfma_f32_16x16x32_bf16(          \
                    FAc[mi], FBc[ni], acc[mi][ni], 0, 0, 0);                    \
        __builtin_amdgcn_s_setprio(0);                                          \
        _Pragma("unroll") for (int g_ = 0; g_ < 4; ++g_) {                      \
            __builtin_amdgcn_sched_group_barrier(0x010, 1, 0); /* 1 VMEM   */   \
            __builtin_amdgcn_sched_group_barrier(0x100, 3, 0); /* 3 DS_READ*/   \
            __builtin_amdgcn_sched_group_barrier(0x008, 8, 0); /* 8 MFMA  */    \
        }                                                                       \
        asm volatile("s_waitcnt vmcnt(4)" ::: "memory");                        \
        __builtin_amdgcn_s_barrier();                                           \
        asm volatile("" ::: "memory");                                          \
    } while (0)

// tail tile: literal T -> all conditionals fold at compile time (R5 semantics).
#define TILE(T, FAc, FBc, FAn, FBn) do {                                        \
        const int t_ = (T);                                                     \
        if (t_ + 3 < NT) {                                                      \
            const int pb_ = (t_ + 3) & 3; const int pk_ = (t_ + 3) * BK;        \
            STAGE_A(pb_, pk_); STAGE_B(pb_, pk_);                               \
        }                                                                       \
        if (t_ + 1 < NT) {                                                      \
            const __bf16* nb_ = &lds[(t_ + 1) & 3][0];                          \
            _Pragma("unroll") for (int mi = 0; mi < 8; ++mi)                    \
                FAn[mi] = *(const bf16x8*)&nb_[aoff + mi * 512];                \
            _Pragma("unroll") for (int ni = 0; ni < 4; ++ni)                    \
                FBn[ni] = *(const bf16x8*)&nb_[boff + ni * 512];                \
        }                                                                       \
        __builtin_amdgcn_s_setprio(1);                                          \
        _Pragma("unroll") for (int mi = 0; mi < 8; ++mi)                        \
            _Pragma("unroll") for (int ni = 0; ni < 4; ++ni)                    \
                acc[mi][ni] = __builtin_amdgcn_mfma_f32_16x16x32_bf16(          \
                    FAc[mi], FBc[ni], acc[mi][ni], 0, 0, 0);                    \
        __builtin_amdgcn_s_setprio(0);                                          \
        if (t_ < NT - 3)       asm volatile("s_waitcnt vmcnt(4)" ::: "memory"); \
        else if (t_ == NT - 3) asm volatile("s_waitcnt vmcnt(0)" ::: "memory"); \
        if (t_ < NT - 1) {                                                      \
            __builtin_amdgcn_s_barrier();                                       \
            asm volatile("" ::: "memory");                                      \
        }                                                                       \
    } while (0)

    // ---- prologue: stage 0,1,2; certify stages 0+1 for ALL waves; frags(0) ----
    STAGE_A(0, 0);   STAGE_B(0, 0);
    STAGE_A(1, 32);  STAGE_B(1, 32);
    STAGE_A(2, 64);  STAGE_B(2, 64);
    asm volatile("s_waitcnt vmcnt(4)" ::: "memory");
    __builtin_amdgcn_s_barrier();
    asm volatile("" ::: "memory");
    {
        const __bf16* nb_ = &lds[0][0];
#pragma unroll
        for (int mi = 0; mi < 8; ++mi) fa0[mi] = *(const bf16x8*)&nb_[aoff + mi * 512];
#pragma unroll
        for (int ni = 0; ni < 4; ++ni) fb0[ni] = *(const bf16x8*)&nb_[boff + ni * 512];
    }

    // main loop: tiles 0..123 (t+3 <= 126 < NT and t+1 <= 124 < NT always)
    for (int t = 0; t < 124; t += 2) {
        TILE_MAIN(t,     fa0, fb0, fa1, fb1);
        TILE_MAIN(t + 1, fa1, fb1, fa0, fb0);
    }
    // tail: tiles 124..127, literal-folded conditionals
    TILE(124, fa0, fb0, fa1, fb1);
    TILE(125, fa1, fb1, fa0, fb0);
    TILE(126, fa0, fb0, fa1, fb1);
    TILE(127, fa1, fb1, fa0, fb0);

    // ---- epilogue: C/D layout col=lane&15, row=(lane>>4)*4+reg  [m89-verified] ----
    float bv[4];
#pragma unroll
    for (int ni = 0; ni < 4; ++ni) bv[ni] = bias[tileN + wn * 64 + ni * 16 + lr];
#pragma unroll
    for (int mi = 0; mi < 8; ++mi) {
#pragma unroll
        for (int ni = 0; ni < 4; ++ni) {
            const int gn = tileN + wn * 64 + ni * 16 + lr;
#pragma unroll
            for (int r = 0; r < 4; ++r) {
                const int gm = tileM + wm * 128 + mi * 16 + lq * 4 + r;
                C[(size_t)gm * N + gn] = acc[mi][ni][r] + bv[ni];
            }
        }
    }
#undef TILE
#undef TILE_MAIN
#undef STAGE_A
#undef STAGE_B
}

extern "C" void kernel_launch(void* const* d_in, const int* in_sizes, int n_in,
                              void* d_out, int out_size, void* d_ws, size_t ws_size,
                              hipStream_t stream) {
    const float* x    = (const float*)d_in[0];   // (4,2048,4096) fp32
    const float* vals = (const float*)d_in[1];   // (NNZ,) fp32
    const float* bias = (const float*)d_in[2];   // (4096,) fp32
    const int*   idx  = (const int*)d_in[3];     // (NNZ,) sorted flat indices
    float* out = (float*)d_out;                  // (4,2048,4096) fp32

    const int nnz = in_sizes[1];
    const int K = IN_F, N = OUT_F;
    const int M = in_sizes[0] / K;               // 8192

    // workspace: [0,32M) W bf16 | [32M,96M) x bf16
    char* ws = (char*)d_ws;
    __bf16* Wb = (__bf16*)ws;
    __bf16* Xb = (__bf16*)(ws + (size_t)32 * 1024 * 1024);

    const int wElems = N * K;                    // 16777216
    const int xElems = M * K;                    // 33554432
    const int n8 = xElems / 8;                   // 4194304 cvt threads
    const int cvtBlocks = n8 / 256;              // 16384
    const int scatBlocks = (nnz + 255) / 256;    // 6554

    hipMemsetAsync(Wb, 0, (size_t)wElems * sizeof(__bf16), stream);
    cvt_and_scatter<<<cvtBlocks + scatBlocks, 256, 0, stream>>>(
        x, Xb, n8, vals, idx, Wb, nnz, cvtBlocks);

    gemm_bf16_bt<<<(M / BM) * (N / BN), 512, 0, stream>>>(Xb, Wb, bias, out, M, N, K);
}

// Round 7
// 453.458 us; speedup vs baseline: 1.1326x; 1.0224x over previous
//
#include <hip/hip_runtime.h>
#include <hip/hip_bf16.h>
#include <stdint.h>

#define IN_F 4096
#define OUT_F 4096

typedef __attribute__((ext_vector_type(8))) __bf16 bf16x8;
typedef __attribute__((ext_vector_type(4))) float f32x4;

__device__ __forceinline__ void gl_lds_16(const void* g, void* l) {
    __builtin_amdgcn_global_load_lds((const __attribute__((address_space(1))) void*)g,
                                     (__attribute__((address_space(3))) void*)l,
                                     16, 0, 0);
}

// ---- x fp32->bf16 (8 elems/thread, 16B loads+stores) ----
__global__ void cvt_x(const float* __restrict__ x, __bf16* __restrict__ Xb, int n8) {
    int i = blockIdx.x * blockDim.x + threadIdx.x;
    if (i < n8) {
        const float4* src = (const float4*)(x + (size_t)i * 8);
        float4 v0 = src[0], v1 = src[1];
        bf16x8 o;
        o[0] = (__bf16)v0.x; o[1] = (__bf16)v0.y; o[2] = (__bf16)v0.z; o[3] = (__bf16)v0.w;
        o[4] = (__bf16)v1.x; o[5] = (__bf16)v1.y; o[6] = (__bf16)v1.z; o[7] = (__bf16)v1.w;
        *(bf16x8*)(Xb + (size_t)i * 8) = o;
    }
}

// ---- sorted-COO scatter into zeroed W (run owner sums fp32, stores bf16) ----
__global__ void scatter_w(const float* __restrict__ vals, const int* __restrict__ idx,
                          __bf16* __restrict__ W, int nnz) {
    int i = blockIdx.x * blockDim.x + threadIdx.x;
    if (i >= nnz) return;
    const int id = idx[i];
    if (i > 0 && idx[i - 1] == id) return;
    float s = vals[i];
    for (int j = i + 1; j < nnz && idx[j] == id; ++j) s += vals[j];
    W[id] = (__bf16)s;
}

// ---- GEMM: C[M,N] = A[M,K] * B[N,K]^T + bias,  bf16 in / fp32 out ----
// 256x256 tile, BK=32, 8 waves (2Mx4N), quad-buffered LDS, prefetch distance 3,
// chunk-XOR swizzle (R4: conflicts=0), register-double-buffered fragments (R5).
// R7: issue-order interleave, done right this time. R6's SGB chain governed a
// region split by setprio() (side-effecting intrinsic between reads and MFMAs)
// so emitted order was still 12 reads -> 32 MFMAs: at barrier release 8 waves
// dump 96 b128 into the LDS queue, it backpressures, waves stall mid-issue and
// never reach their (independent!) MFMAs -> pipes serialize (measured 2231
// cyc/tile = 1024 MFMA + 1152 LDS + overhead, 3 rounds running).
// Fix: (a) NO setprio in loop; (b) source-order interleave 4 x {<=2 VMEM,
// 3 DS_READ, 8 MFMA}; (c) SGB chain in the same unbroken region; (d) read
// order FA0,FA1,FB0 | FB1..3 | FA2..4 | FA5..7 so next tile's first MFMA
// group needs only the first 6 reads (smaller entry lgkmcnt).
// Sync schedule unchanged (3 rounds verified): vmcnt(4) certifies STAGE(t+2)
// before barrier@t; reads@t (buf (t+1)&3) covered by barrier@t-1; WAR on
// STAGE@t's buffer is 2 barriers upstream.
#define BM 256
#define BN 256
#define BK 32
#define NT (IN_F / BK)   // 128 K-tiles

__global__ __launch_bounds__(512, 2) void gemm_bf16_bt(
    const __bf16* __restrict__ A, const __bf16* __restrict__ B,
    const float* __restrict__ bias, float* __restrict__ C,
    int M, int N, int K)
{
    __shared__ __align__(128) __bf16 lds[4][16384];

    const int t512 = threadIdx.x;          // 0..511
    const int wave = t512 >> 6;            // 0..7
    const int lane = t512 & 63;
    const int wm = wave >> 2;              // 0..1  (M half)
    const int wn = wave & 3;               // 0..3  (N quarter)
    const int lq = lane >> 4;              // 0..3
    const int lr = lane & 15;              // 0..15

    // XCD swizzle: grid is exactly 512 = 8 XCDs x 64 contiguous slots
    const int bid  = blockIdx.x;
    const int wgid = (bid & 7) * 64 + (bid >> 3);
    const int mt = wgid >> 4;              // 0..31
    const int nt = wgid & 15;              // 0..15
    const int tileM = mt * BM;
    const int tileN = nt * BN;

    // staging: thread u covers row u>>2; DEST chunk u&3 linear (global_load_lds),
    // SOURCE chunk swizzle-inverse: c = (u&3) ^ ((row>>1)&3) = (u&3) ^ ((u>>3)&3).
    const int srow = t512 >> 2;            // 0..127
    const int scol = ((t512 & 3) ^ ((t512 >> 3) & 3)) * 8;

    const __bf16* gA0 = A + (size_t)(tileM + srow) * K + scol;
    const __bf16* gA1 = A + (size_t)(tileM + 128 + srow) * K + scol;
    const __bf16* gB0 = B + (size_t)(tileN + srow) * K + scol;
    const __bf16* gB1 = B + (size_t)(tileN + 128 + srow) * K + scol;

#define STAGE_A(buf, k0) do { \
        gl_lds_16(gA0 + (k0), &lds[buf][0]    + t512 * 8); \
        gl_lds_16(gA1 + (k0), &lds[buf][4096] + t512 * 8); } while (0)
#define STAGE_B(buf, k0) do { \
        gl_lds_16(gB0 + (k0), &lds[buf][8192]         + t512 * 8); \
        gl_lds_16(gB1 + (k0), &lds[buf][8192 + 4096]  + t512 * 8); } while (0)

    // fragment read offsets with matching XOR (row bases are multiples of 16):
    const int cswz = (lq ^ ((lr >> 1) & 3)) * 8;
    const int aoff = (wm * 128 + lr) * BK + cswz;            // fa[mi] at +mi*512
    const int boff = 8192 + (wn * 64 + lr) * BK + cswz;      // fb[ni] at +ni*512

    f32x4 acc[8][4] = {};
    bf16x8 fa0[8], fb0[4], fa1[8], fb1[4];

#define MM2(FAc, FBc, MI0, MI1) do {                                            \
        _Pragma("unroll") for (int ni_ = 0; ni_ < 4; ++ni_)                     \
            acc[MI0][ni_] = __builtin_amdgcn_mfma_f32_16x16x32_bf16(            \
                FAc[MI0], FBc[ni_], acc[MI0][ni_], 0, 0, 0);                    \
        _Pragma("unroll") for (int ni_ = 0; ni_ < 4; ++ni_)                     \
            acc[MI1][ni_] = __builtin_amdgcn_mfma_f32_16x16x32_bf16(            \
                FAc[MI1], FBc[ni_], acc[MI1][ni_], 0, 0, 0);                    \
    } while (0)

// main-loop tile (tiles 0..123: always stage + always read-ahead), interleaved.
#define TILE_MAIN(T, FAc, FBc, FAn, FBn) do {                                   \
        const int t_ = (T);                                                     \
        const int pb_ = (t_ + 3) & 3; const int pk_ = (t_ + 3) * BK;            \
        const __bf16* nb_ = &lds[(t_ + 1) & 3][0];                              \
        /* G0: 2 VMEM, 3 DS, 8 MFMA */                                          \
        STAGE_A(pb_, pk_);                                                      \
        FAn[0] = *(const bf16x8*)&nb_[aoff];                                    \
        FAn[1] = *(const bf16x8*)&nb_[aoff + 512];                              \
        FBn[0] = *(const bf16x8*)&nb_[boff];                                    \
        MM2(FAc, FBc, 0, 1);                                                    \
        /* G1: 2 VMEM, 3 DS, 8 MFMA */                                          \
        STAGE_B(pb_, pk_);                                                      \
        FBn[1] = *(const bf16x8*)&nb_[boff + 512];                              \
        FBn[2] = *(const bf16x8*)&nb_[boff + 1024];                             \
        FBn[3] = *(const bf16x8*)&nb_[boff + 1536];                             \
        MM2(FAc, FBc, 2, 3);                                                    \
        /* G2: 3 DS, 8 MFMA */                                                  \
        FAn[2] = *(const bf16x8*)&nb_[aoff + 1024];                             \
        FAn[3] = *(const bf16x8*)&nb_[aoff + 1536];                             \
        FAn[4] = *(const bf16x8*)&nb_[aoff + 2048];                             \
        MM2(FAc, FBc, 4, 5);                                                    \
        /* G3: 3 DS, 8 MFMA */                                                  \
        FAn[5] = *(const bf16x8*)&nb_[aoff + 2560];                             \
        FAn[6] = *(const bf16x8*)&nb_[aoff + 3072];                             \
        FAn[7] = *(const bf16x8*)&nb_[aoff + 3584];                             \
        MM2(FAc, FBc, 6, 7);                                                    \
        /* SGB prescription for THIS region (no setprio/asm inside region) */   \
        __builtin_amdgcn_sched_group_barrier(0x030, 2, 0); /* 2 VMEM  */        \
        __builtin_amdgcn_sched_group_barrier(0x100, 3, 0); /* 3 DS_rd */        \
        __builtin_amdgcn_sched_group_barrier(0x008, 8, 0); /* 8 MFMA  */        \
        __builtin_amdgcn_sched_group_barrier(0x030, 2, 0);                      \
        __builtin_amdgcn_sched_group_barrier(0x100, 3, 0);                      \
        __builtin_amdgcn_sched_group_barrier(0x008, 8, 0);                      \
        __builtin_amdgcn_sched_group_barrier(0x100, 3, 0);                      \
        __builtin_amdgcn_sched_group_barrier(0x008, 8, 0);                      \
        __builtin_amdgcn_sched_group_barrier(0x100, 3, 0);                      \
        __builtin_amdgcn_sched_group_barrier(0x008, 8, 0);                      \
        asm volatile("s_waitcnt vmcnt(4)" ::: "memory");                        \
        __builtin_amdgcn_s_barrier();                                           \
        asm volatile("" ::: "memory");                                          \
    } while (0)

// tail tile: literal T -> all conditionals fold at compile time.
#define TILE(T, FAc, FBc, FAn, FBn) do {                                        \
        const int t_ = (T);                                                     \
        if (t_ + 3 < NT) {                                                      \
            const int pb_ = (t_ + 3) & 3; const int pk_ = (t_ + 3) * BK;        \
            STAGE_A(pb_, pk_); STAGE_B(pb_, pk_);                               \
        }                                                                       \
        if (t_ + 1 < NT) {                                                      \
            const __bf16* nb_ = &lds[(t_ + 1) & 3][0];                          \
            _Pragma("unroll") for (int mi = 0; mi < 8; ++mi)                    \
                FAn[mi] = *(const bf16x8*)&nb_[aoff + mi * 512];                \
            _Pragma("unroll") for (int ni = 0; ni < 4; ++ni)                    \
                FBn[ni] = *(const bf16x8*)&nb_[boff + ni * 512];                \
        }                                                                       \
        _Pragma("unroll") for (int mi = 0; mi < 8; ++mi)                        \
            _Pragma("unroll") for (int ni = 0; ni < 4; ++ni)                    \
                acc[mi][ni] = __builtin_amdgcn_mfma_f32_16x16x32_bf16(          \
                    FAc[mi], FBc[ni], acc[mi][ni], 0, 0, 0);                    \
        if (t_ < NT - 3)       asm volatile("s_waitcnt vmcnt(4)" ::: "memory"); \
        else if (t_ == NT - 3) asm volatile("s_waitcnt vmcnt(0)" ::: "memory"); \
        if (t_ < NT - 1) {                                                      \
            __builtin_amdgcn_s_barrier();                                       \
            asm volatile("" ::: "memory");                                      \
        }                                                                       \
    } while (0)

    // ---- prologue: stage 0,1,2; certify stages 0+1 for ALL waves; frags(0) ----
    STAGE_A(0, 0);   STAGE_B(0, 0);
    STAGE_A(1, 32);  STAGE_B(1, 32);
    STAGE_A(2, 64);  STAGE_B(2, 64);
    asm volatile("s_waitcnt vmcnt(4)" ::: "memory");
    __builtin_amdgcn_s_barrier();
    asm volatile("" ::: "memory");
    {
        const __bf16* nb_ = &lds[0][0];
#pragma unroll
        for (int mi = 0; mi < 8; ++mi) fa0[mi] = *(const bf16x8*)&nb_[aoff + mi * 512];
#pragma unroll
        for (int ni = 0; ni < 4; ++ni) fb0[ni] = *(const bf16x8*)&nb_[boff + ni * 512];
    }

    // main loop: tiles 0..123 (t+3 <= 126 < NT and t+1 <= 124 < NT always)
    for (int t = 0; t < 124; t += 2) {
        TILE_MAIN(t,     fa0, fb0, fa1, fb1);
        TILE_MAIN(t + 1, fa1, fb1, fa0, fb0);
    }
    // tail: tiles 124..127, literal-folded conditionals
    TILE(124, fa0, fb0, fa1, fb1);
    TILE(125, fa1, fb1, fa0, fb0);
    TILE(126, fa0, fb0, fa1, fb1);
    TILE(127, fa1, fb1, fa0, fb0);

    // ---- epilogue: C/D layout col=lane&15, row=(lane>>4)*4+reg  [m89-verified] ----
    float bv[4];
#pragma unroll
    for (int ni = 0; ni < 4; ++ni) bv[ni] = bias[tileN + wn * 64 + ni * 16 + lr];
#pragma unroll
    for (int mi = 0; mi < 8; ++mi) {
#pragma unroll
        for (int ni = 0; ni < 4; ++ni) {
            const int gn = tileN + wn * 64 + ni * 16 + lr;
#pragma unroll
            for (int r = 0; r < 4; ++r) {
                const int gm = tileM + wm * 128 + mi * 16 + lq * 4 + r;
                C[(size_t)gm * N + gn] = acc[mi][ni][r] + bv[ni];
            }
        }
    }
#undef TILE
#undef TILE_MAIN
#undef MM2
#undef STAGE_A
#undef STAGE_B
}

extern "C" void kernel_launch(void* const* d_in, const int* in_sizes, int n_in,
                              void* d_out, int out_size, void* d_ws, size_t ws_size,
                              hipStream_t stream) {
    const float* x    = (const float*)d_in[0];   // (4,2048,4096) fp32
    const float* vals = (const float*)d_in[1];   // (NNZ,) fp32
    const float* bias = (const float*)d_in[2];   // (4096,) fp32
    const int*   idx  = (const int*)d_in[3];     // (NNZ,) sorted flat indices
    float* out = (float*)d_out;                  // (4,2048,4096) fp32

    const int nnz = in_sizes[1];
    const int K = IN_F, N = OUT_F;
    const int M = in_sizes[0] / K;               // 8192

    // workspace: [0,32M) W bf16 | [32M,96M) x bf16
    char* ws = (char*)d_ws;
    __bf16* Wb = (__bf16*)ws;
    __bf16* Xb = (__bf16*)(ws + (size_t)32 * 1024 * 1024);

    const int wElems = N * K;                    // 16777216
    const int xElems = M * K;                    // 33554432
    const int n8 = xElems / 8;                   // 4194304 cvt threads
    const int cvtBlocks = n8 / 256;              // 16384
    const int scatBlocks = (nnz + 255) / 256;    // 6554

    // split dispatches (R7): identical semantics to the fused pre-pass, but each
    // kernel gets its own rocprof row so the ~226us non-GEMM time can be decomposed.
    hipMemsetAsync(Wb, 0, (size_t)wElems * sizeof(__bf16), stream);
    cvt_x<<<cvtBlocks, 256, 0, stream>>>(x, Xb, n8);
    scatter_w<<<scatBlocks, 256, 0, stream>>>(vals, idx, Wb, nnz);

    gemm_bf16_bt<<<(M / BM) * (N / BN), 512, 0, stream>>>(Xb, Wb, bias, out, M, N, K);
}